// Round 4
// baseline (586.422 us; speedup 1.0000x reference)
//
#include <hip/hip_runtime.h>
#include <math.h>

// Problem constants (Posit_Drmm_Modeler)
#define VB  64      // batch
#define NSS 50      // sentences per doc
#define LSS 60      // sentence length
#define LQQ 32      // question length
#define DD  300     // embedding dim
#define FF  256     // filters

#define SEST 312    // seb row stride (bf16): 312%8==0 -> 16B rows
#define SROWS 66    // rows 60..65 zero (conv A-frag overrun + M-pad)
#define SCST 264    // scb row stride (bf16)
#define SIMST 66    // sim row stride (fp32)
#define KKC 29      // conv K-steps (K=928 incl. stride pads; filter zeros neutralize)
#define KKI 10      // sim_ins K-steps (K=320, qe zero-padded)
#define KKS 8       // sim_sen K-steps (K=256)

typedef __attribute__((ext_vector_type(8))) short bfrag;   // 8 x bf16 (4 VGPRs)
typedef __attribute__((ext_vector_type(4))) float ffrag;   // 4 x f32 acc

__device__ __forceinline__ unsigned short f2bf(float v) {
    unsigned int x = __float_as_uint(v);
    x += 0x7fffu + ((x >> 16) & 1u);          // RNE
    return (unsigned short)(x >> 16);
}
__device__ __forceinline__ float bf2f(unsigned short u) {
    return __uint_as_float(((unsigned int)u) << 16);
}

// build one conv B-fragment (8 k-consecutive bf16 of filter f) from raw fp32 filters.
// k -> (t=k/312, d=k%312); zero if t>=3 or d>=300. k0 is 8-aligned so t is constant.
__device__ __forceinline__ bfrag build_bfrag(const float* __restrict__ filters, int f, int k0) {
    int t = k0 / SEST, d0 = k0 - t * SEST;
    union { bfrag b; unsigned short s[8]; } u;
    if (t < 3 && d0 < DD) {
        const float* p = filters + f * 900 + t * DD + d0;
        float4 v0 = *(const float4*)p;
        u.s[0] = f2bf(v0.x); u.s[1] = f2bf(v0.y); u.s[2] = f2bf(v0.z); u.s[3] = f2bf(v0.w);
        if (d0 + 4 < DD) {
            float4 v1 = *(const float4*)(p + 4);
            u.s[4] = f2bf(v1.x); u.s[5] = f2bf(v1.y); u.s[6] = f2bf(v1.z); u.s[7] = f2bf(v1.w);
        } else {
            u.s[4] = 0; u.s[5] = 0; u.s[6] = 0; u.s[7] = 0;
        }
    } else {
        #pragma unroll
        for (int i = 0; i < 8; ++i) u.s[i] = 0;
    }
    return u.b;
}

// ---------------- k_prep: fused filter-frag prep (blocks >= VB) + per-b question prep (blocks < VB)
// filt_frag layout: [kk(29)][nt(16)][lane(64)][j(8)]; value = filt[f=nt*16+(lane&15)][k=kk*32+quad*8+j]
__global__ __launch_bounds__(512) void k_prep(const int* __restrict__ question,
                                              const float* __restrict__ embeds,
                                              const float* __restrict__ filters,
                                              unsigned short* __restrict__ filt_frag,
                                              unsigned short* __restrict__ qe_frag,
                                              unsigned short* __restrict__ qc_frag,
                                              float* __restrict__ q_inv,
                                              float* __restrict__ qc_inv) {
    const int tid = threadIdx.x;
    if (blockIdx.x >= VB) {
        // ---- fprep chunk: 116 blocks x 512 threads x 4 ushorts = 237,568 (exact)
        int idx0 = ((blockIdx.x - VB) * 512 + tid) * 4;
        int j0 = idx0 & 7, ln = (idx0 >> 3) & 63, nt = (idx0 >> 9) & 15, kk = idx0 >> 13;
        int f = nt * 16 + (ln & 15);
        int k0 = kk * 32 + ((ln >> 4) << 3) + j0;
        int t = k0 / SEST, d0 = k0 - t * SEST;
        ushort4 h = {0, 0, 0, 0};
        if (t < 3 && d0 < DD) {
            float4 v = *(const float4*)(filters + f * 900 + t * DD + d0);
            h.x = f2bf(v.x); h.y = f2bf(v.y); h.z = f2bf(v.z); h.w = f2bf(v.w);
        }
        *(ushort4*)(filt_frag + idx0) = h;
        return;
    }
    // ---- question prep for batch b
    const int b = blockIdx.x, lane = tid & 63, w = tid >> 6;
    const int quad = lane >> 4, m16 = lane & 15;
    __shared__ __align__(16) unsigned short qeb[34 * SEST];   // 21,216 B (rows 32..33 zero)
    __shared__ __align__(16) unsigned short qcb[LQQ * SCST];  // 16,896 B
    __shared__ float qpn[LQQ][4];                             // per-N-tile-group sumsq partials
    const int* qrow = question + b * LQQ;
    {   // zero col tails (rows 0..31, d 300..311) and rows 32..33
        ushort4 z4 = {0, 0, 0, 0};
        for (int i = tid; i < 96; i += 512) {
            int r = i / 3, c = 300 + (i - r * 3) * 4;
            *(ushort4*)(qeb + r * SEST + c) = z4;
        }
        for (int i = tid; i < 156; i += 512) {
            int r = i / 78, c = (i - r * 78) * 4;
            *(ushort4*)(qeb + (LQQ + r) * SEST + c) = z4;
        }
    }
    // gather + q_inv fused: 16-thread group per row, fp32 sumsq in regs
    {
        const int g = tid >> 4, part = tid & 15;   // 32 groups of 16 threads
        const float* erow = embeds + (size_t)qrow[g] * DD;
        float s = 0.f;
        for (int c = part * 4; c < DD; c += 64) {
            float4 v = *(const float4*)(erow + c);
            s += v.x * v.x + v.y * v.y + v.z * v.z + v.w * v.w;
            ushort4 h;
            h.x = f2bf(v.x); h.y = f2bf(v.y); h.z = f2bf(v.z); h.w = f2bf(v.w);
            *(ushort4*)(qeb + g * SEST + c) = h;
        }
        s += __shfl_down(s, 8, 16);
        s += __shfl_down(s, 4, 16);
        s += __shfl_down(s, 2, 16);
        s += __shfl_down(s, 1, 16);
        if (part == 0) q_inv[b * LQQ + g] = 1.f / sqrtf(s);
    }
    __syncthreads();
    // qe A-fragments: [kk(10)][mt(2)][lane(64)][j(8)] per b (pure bf16 copy)
    for (int idx = tid; idx < KKI * 2 * 512; idx += 512) {
        int j = idx & 7, ln = (idx >> 3) & 63, mt = (idx >> 9) & 1, kk = idx >> 10;
        int q = mt * 16 + (ln & 15);
        int k = kk * 32 + ((ln >> 4) << 3) + j;
        qe_frag[(size_t)b * (KKI * 2 * 512) + idx] = (k < DD) ? qeb[q * SEST + k] : (unsigned short)0;
    }
    // ===== question conv GEMM: C[q=32][f=256] = qeb-window[32x928] x filt[928x256] =====
    // 8 waves: wave w owns M-tile (w&1), N-tiles (w>>1)*4 .. +3; B built from raw filters
    const int mtq = w & 1, w4 = (w >> 1) * 4;
    ffrag acc[4];
    #pragma unroll
    for (int i = 0; i < 4; ++i) acc[i] = (ffrag)0.f;
    for (int kk = 0; kk < KKC; ++kk) {
        const int kb = kk * 32 + quad * 8;
        bfrag bb[4];
        #pragma unroll
        for (int i = 0; i < 4; ++i)
            bb[i] = build_bfrag(filters, (w4 + i) * 16 + m16, kb);
        bfrag a0 = *(const bfrag*)(qeb + (mtq * 16 + m16) * SEST + kb);
        #pragma unroll
        for (int i = 0; i < 4; ++i)
            acc[i] = __builtin_amdgcn_mfma_f32_16x16x32_bf16(a0, bb[i], acc[i], 0, 0, 0);
    }
    // C -> qcb bf16 [q][f] + per-wave partial sumsq (fp32) for qc_inv
    #pragma unroll
    for (int i = 0; i < 4; ++i) {
        int f = (w4 + i) * 16 + m16;
        #pragma unroll
        for (int r = 0; r < 4; ++r) {
            int q = mtq * 16 + quad * 4 + r;
            qcb[q * SCST + f] = f2bf(acc[i][r]);
        }
    }
    // Each q belongs to exactly one M-tile parity; waves of that parity have w>>1 in [0,4)
    // covering disjoint 64-filter groups -> qpn[q][w>>1] is fully and uniquely written.
    #pragma unroll
    for (int r = 0; r < 4; ++r) {
        float s = acc[0][r] * acc[0][r] + acc[1][r] * acc[1][r]
                + acc[2][r] * acc[2][r] + acc[3][r] * acc[3][r];
        s += __shfl_down(s, 8, 16);
        s += __shfl_down(s, 4, 16);
        s += __shfl_down(s, 2, 16);
        s += __shfl_down(s, 1, 16);
        if (m16 == 0) qpn[mtq * 16 + quad * 4 + r][w >> 1] = s;
    }
    __syncthreads();
    if (tid < LQQ) {
        float s = qpn[tid][0] + qpn[tid][1] + qpn[tid][2] + qpn[tid][3];
        qc_inv[b * LQQ + tid] = 1.f / sqrtf(s);
    }
    // qc A-fragments: [kk(8)][mt(2)][lane(64)][j(8)] per b
    for (int idx = tid; idx < KKS * 2 * 512; idx += 512) {
        int j = idx & 7, ln = (idx >> 3) & 63, mt = (idx >> 9) & 1, kk = idx >> 10;
        int q = mt * 16 + (ln & 15);
        int k = kk * 32 + ((ln >> 4) << 3) + j;
        qc_frag[(size_t)b * (KKS * 2 * 512) + idx] = qcb[q * SCST + k];
    }
}

// one conv K-step: 4 A-frags from LDS + 8 MFMA with prefetched B regs
#define CONV_STEP(KKV, BB0, BB1) do {                                              \
    const int kb_ = (KKV) * 32 + quad * 8;                                         \
    bfrag a0_ = *(const bfrag*)(seb + (m16) * SEST + kb_);                         \
    bfrag a1_ = *(const bfrag*)(seb + (16 + m16) * SEST + kb_);                    \
    bfrag a2_ = *(const bfrag*)(seb + (32 + m16) * SEST + kb_);                    \
    bfrag a3_ = *(const bfrag*)(seb + (48 + m16) * SEST + kb_);                    \
    __builtin_amdgcn_s_setprio(1);                                                 \
    acc[0][0] = __builtin_amdgcn_mfma_f32_16x16x32_bf16(a0_, BB0, acc[0][0], 0, 0, 0); \
    acc[0][1] = __builtin_amdgcn_mfma_f32_16x16x32_bf16(a0_, BB1, acc[0][1], 0, 0, 0); \
    acc[1][0] = __builtin_amdgcn_mfma_f32_16x16x32_bf16(a1_, BB0, acc[1][0], 0, 0, 0); \
    acc[1][1] = __builtin_amdgcn_mfma_f32_16x16x32_bf16(a1_, BB1, acc[1][1], 0, 0, 0); \
    acc[2][0] = __builtin_amdgcn_mfma_f32_16x16x32_bf16(a2_, BB0, acc[2][0], 0, 0, 0); \
    acc[2][1] = __builtin_amdgcn_mfma_f32_16x16x32_bf16(a2_, BB1, acc[2][1], 0, 0, 0); \
    acc[3][0] = __builtin_amdgcn_mfma_f32_16x16x32_bf16(a3_, BB0, acc[3][0], 0, 0, 0); \
    acc[3][1] = __builtin_amdgcn_mfma_f32_16x16x32_bf16(a3_, BB1, acc[3][1], 0, 0, 0); \
    __builtin_amdgcn_s_setprio(0);                                                 \
} while (0)

// ---------------- k_sent: fused per-(b,n), 512 threads / 8 waves, 3 blocks/CU, 4 barriers
__global__ __launch_bounds__(512, 6) void k_sent(
    const int* __restrict__ sentences, const int* __restrict__ question,
    const float* __restrict__ embeds,
    const unsigned short* __restrict__ filt_frag,
    const unsigned short* __restrict__ qe_frag,
    const unsigned short* __restrict__ qc_frag,
    const float* __restrict__ q_inv, const float* __restrict__ qc_inv,
    const float* __restrict__ W6, const float* __restrict__ b1,
    float* __restrict__ d_out) {
    const int blk = blockIdx.x;
    const int b = blk / NSS, n = blk - b * NSS;
    const int tid = threadIdx.x, lane = tid & 63, w = tid >> 6;     // w in [0,8)
    const int quad = lane >> 4, m16 = lane & 15;
    const int w2 = w * 2;

    __shared__ __align__(16) unsigned short seb[SROWS * SEST]; // 41,184 B; overlaid by scb after conv
    __shared__ __align__(16) float sim[LQQ * SIMST];           // 8,448 B
    __shared__ float sinv[64];
    __shared__ float pnorm[64][8];                             // per-wave conv-row sumsq partials
    __shared__ int sid[64];
    __shared__ int qid[LQQ];
    __shared__ float qm[LQQ], qiv[LQQ], qciv[LQQ];
    unsigned short* scb = seb;   // overlay: conv output [l][f] bf16 (60+4 zero rows x 264)

    // early prefetch of first 3 conv B-fragment pairs (independent of LDS)
    const bfrag* fF = (const bfrag*)filt_frag;
    bfrag pa0 = fF[(0 * 16 + w2) * 64 + lane], pb0 = fF[(0 * 16 + w2 + 1) * 64 + lane];
    bfrag pa1 = fF[(1 * 16 + w2) * 64 + lane], pb1 = fF[(1 * 16 + w2 + 1) * 64 + lane];
    bfrag pa2 = fF[(2 * 16 + w2) * 64 + lane], pb2 = fF[(2 * 16 + w2 + 1) * 64 + lane];

    const int* srow = sentences + ((size_t)b * NSS + n) * LSS;
    if (tid < 64) sid[tid] = (tid < LSS) ? srow[tid] : 0;
    if (tid < LQQ) {
        int qi = question[b * LQQ + tid];
        qid[tid] = qi; qm[tid] = qi > 0 ? 1.f : 0.f;
        qiv[tid] = q_inv[b * LQQ + tid]; qciv[tid] = qc_inv[b * LQQ + tid];
    }
    // ======== P0: zero-fill + gather + fused row norms (8-thread group per row) ========
    {
        ushort4 z4 = {0, 0, 0, 0};
        for (int i = tid; i < 180; i += 512) {                 // tails d 300..311, rows 0..59
            int r = i / 3, c = 300 + (i - r * 3) * 4;
            *(ushort4*)(seb + r * SEST + c) = z4;
        }
        for (int i = tid; i < 468; i += 512) {                 // rows 60..65 full
            int r = i / 78, c = (i - r * 78) * 4;
            *(ushort4*)(seb + (60 + r) * SEST + c) = z4;
        }
    }
    {
        const int g = tid >> 3, part = tid & 7;                // 64 groups of 8
        if (g < LSS) {
            const float* erow = embeds + (size_t)srow[g] * DD;
            float s = 0.f;
            for (int c = part * 4; c < DD; c += 32) {
                float4 v = *(const float4*)(erow + c);
                s += v.x * v.x + v.y * v.y + v.z * v.z + v.w * v.w;
                ushort4 h;
                h.x = f2bf(v.x); h.y = f2bf(v.y); h.z = f2bf(v.z); h.w = f2bf(v.w);
                *(ushort4*)(seb + g * SEST + c) = h;
            }
            s += __shfl_down(s, 4, 8);
            s += __shfl_down(s, 2, 8);
            s += __shfl_down(s, 1, 8);
            if (part == 0) sinv[g] = 1.f / sqrtf(s);
        } else if (part == 0) {
            sinv[g] = 0.f;                                     // rows 60..63
        }
    }
    __syncthreads();   // ---- barrier A

    // ======== P1: conv GEMM (depth-3 B prefetch) + sim_ins GEMM ========
    ffrag acc[4][2];
    #pragma unroll
    for (int mt = 0; mt < 4; ++mt)
        #pragma unroll
        for (int i = 0; i < 2; ++i) acc[mt][i] = (ffrag)0.f;
    {
        for (int kk = 0; kk < 24; kk += 3) {   // kk = 0,3,...,21 -> steps 0..23, prefetch to 26
            bfrag na0 = fF[((kk + 3) * 16 + w2) * 64 + lane];
            bfrag nb0 = fF[((kk + 3) * 16 + w2 + 1) * 64 + lane];
            CONV_STEP(kk, pa0, pb0);
            bfrag na1 = fF[((kk + 4) * 16 + w2) * 64 + lane];
            bfrag nb1 = fF[((kk + 4) * 16 + w2 + 1) * 64 + lane];
            CONV_STEP(kk + 1, pa1, pb1);
            bfrag na2 = fF[((kk + 5) * 16 + w2) * 64 + lane];
            bfrag nb2 = fF[((kk + 5) * 16 + w2 + 1) * 64 + lane];
            CONV_STEP(kk + 2, pa2, pb2);
            pa0 = na0; pb0 = nb0; pa1 = na1; pb1 = nb1; pa2 = na2; pb2 = nb2;
        }
        // steps 24..28: 24,25,26 already in regs; load 27,28
        bfrag ta = fF[(27 * 16 + w2) * 64 + lane], tb = fF[(27 * 16 + w2 + 1) * 64 + lane];
        bfrag ua = fF[(28 * 16 + w2) * 64 + lane], ub = fF[(28 * 16 + w2 + 1) * 64 + lane];
        CONV_STEP(24, pa0, pb0);
        CONV_STEP(25, pa1, pb1);
        CONV_STEP(26, pa2, pb2);
        CONV_STEP(27, ta, tb);
        CONV_STEP(28, ua, ub);
    }
    // sim_ins: C[q=32][l=64] = qe[32x320] x seb^T; wave w owns 1 tile
    {
        const int mt = w >> 2, nt = w & 3;
        const bfrag* qF = (const bfrag*)qe_frag + ((size_t)b * KKI * 2 + mt) * 64 + lane;
        const unsigned short* sebr = seb + (nt * 16 + m16) * SEST + quad * 8;
        ffrag c0 = (ffrag)0.f;
        bfrag aq0 = qF[0];
        for (int kk = 0; kk < KKI; kk += 2) {
            bfrag aq1 = qF[(kk + 1) * 128];
            bfrag bL0 = *(const bfrag*)(sebr + kk * 32);
            c0 = __builtin_amdgcn_mfma_f32_16x16x32_bf16(aq0, bL0, c0, 0, 0, 0);
            if (kk + 2 < KKI) aq0 = qF[(kk + 2) * 128];
            bfrag bL1 = *(const bfrag*)(sebr + (kk + 1) * 32);
            c0 = __builtin_amdgcn_mfma_f32_16x16x32_bf16(aq1, bL1, c0, 0, 0, 0);
        }
        const int l_ = nt * 16 + m16;
        const float sm = sinv[l_] * (sid[l_] > 0 ? 1.f : 0.f);
        #pragma unroll
        for (int r = 0; r < 4; ++r) {
            int q = mt * 16 + quad * 4 + r;
            sim[q * SIMST + l_] = c0[r] * (qiv[q] * qm[q]) * sm;
        }
    }
    __syncthreads();   // ---- barrier B (all seb reads done; sim_ins visible)

    // ======== P2: conv C -> scb bf16 + pnorm partials + pool_ins (wave0 regs) ========
    float fq0 = 0.f, fq1 = 0.f, fq2 = 0.f, fq3 = 0.f;          // wave0 lanes<32: featq
    if (tid < 256) {
        ushort4 z4 = {0, 0, 0, 0};
        int r4 = 60 + (tid >> 6), c4 = (tid & 63) * 4;
        *(ushort4*)(scb + r4 * SCST + c4) = z4;
    }
    #pragma unroll
    for (int mt = 0; mt < 4; ++mt)
        #pragma unroll
        for (int i = 0; i < 2; ++i) {
            int f = (w2 + i) * 16 + m16;
            #pragma unroll
            for (int r = 0; r < 4; ++r) {
                int l = mt * 16 + quad * 4 + r;
                scb[l * SCST + f] = f2bf(acc[mt][i][r]);
            }
        }
    // per-wave conv-row sumsq partials (fp32, from regs); wave w covers all 64 rows
    #pragma unroll
    for (int mt = 0; mt < 4; ++mt)
        #pragma unroll
        for (int r = 0; r < 4; ++r) {
            float s = acc[mt][0][r] * acc[mt][0][r] + acc[mt][1][r] * acc[mt][1][r];
            s += __shfl_down(s, 8, 16);
            s += __shfl_down(s, 4, 16);
            s += __shfl_down(s, 2, 16);
            s += __shfl_down(s, 1, 16);
            if (m16 == 0) pnorm[mt * 16 + quad * 4 + r][w] = s;
        }
    if (tid < LQQ) {   // pool_ins + exact-match channel, results in registers
        int q = tid;
        float t0 = -1e30f, t1 = -1e30f, t2 = -1e30f, t3 = -1e30f, t4 = -1e30f;
        for (int l = 0; l < LSS; ++l) {
            float v = sim[q * SIMST + l];
            if (v > t4) {
                if (v > t0)      { t4 = t3; t3 = t2; t2 = t1; t1 = t0; t0 = v; }
                else if (v > t1) { t4 = t3; t3 = t2; t2 = t1; t1 = v; }
                else if (v > t2) { t4 = t3; t3 = t2; t2 = v; }
                else if (v > t3) { t4 = t3; t3 = v; }
                else               t4 = v;
            }
        }
        fq0 = t0;
        fq1 = (t0 + t1 + t2 + t3 + t4) * 0.2f;
        int qi = qid[q], c = 0;
        for (int l = 0; l < LSS; ++l) c += (sid[l] == qi) ? 1 : 0;
        fq2 = c > 0 ? 1.f : 0.f;
        fq3 = (float)(c < 5 ? c : 5) * 0.2f;
    }
    __syncthreads();   // ---- barrier C (scb + pnorm visible; pool_ins reads done)

    // ======== P3: sim_sen GEMM: C[q=32][l=64] = qc[32x256] x scb^T ========
    {
        const int mt = w >> 2, nt = w & 3;
        const bfrag* qF = (const bfrag*)qc_frag + ((size_t)b * KKS * 2 + mt) * 64 + lane;
        const unsigned short* scbr = scb + (nt * 16 + m16) * SCST + quad * 8;
        ffrag c0 = (ffrag)0.f;
        bfrag aq0 = qF[0];
        for (int kk = 0; kk < KKS; kk += 2) {
            bfrag aq1 = qF[(kk + 1) * 128];
            bfrag bL0 = *(const bfrag*)(scbr + kk * 32);
            c0 = __builtin_amdgcn_mfma_f32_16x16x32_bf16(aq0, bL0, c0, 0, 0, 0);
            if (kk + 2 < KKS) aq0 = qF[(kk + 2) * 128];
            bfrag bL1 = *(const bfrag*)(scbr + (kk + 1) * 32);
            c0 = __builtin_amdgcn_mfma_f32_16x16x32_bf16(aq1, bL1, c0, 0, 0, 0);
        }
        const int l_ = nt * 16 + m16;
        float ssum = 0.f;
        #pragma unroll
        for (int t = 0; t < 8; ++t) ssum += pnorm[l_][t];
        const float sm = (1.f / sqrtf(ssum)) * (sid[l_] > 0 ? 1.f : 0.f);
        #pragma unroll
        for (int r = 0; r < 4; ++r) {
            int q = mt * 16 + quad * 4 + r;
            sim[q * SIMST + l_] = c0[r] * (qciv[q] * qm[q]) * sm;
        }
    }
    __syncthreads();   // ---- barrier D (sim_sen visible)

    // ======== P4: pool_sen + linear + sigmoid + reduce (wave 0 only) ========
    if (w == 0) {
        float prv = 0.f;
        if (lane < LQQ) {
            int q = lane;
            float t0 = -1e30f, t1 = -1e30f, t2 = -1e30f, t3 = -1e30f, t4 = -1e30f;
            for (int l = 0; l < LSS; ++l) {
                float v = sim[q * SIMST + l];
                if (v > t4) {
                    if (v > t0)      { t4 = t3; t3 = t2; t2 = t1; t1 = t0; t0 = v; }
                    else if (v > t1) { t4 = t3; t3 = t2; t2 = t1; t1 = v; }
                    else if (v > t2) { t4 = t3; t3 = t2; t2 = v; }
                    else if (v > t3) { t4 = t3; t3 = v; }
                    else               t4 = v;
                }
            }
            float smax = t0, smean = (t0 + t1 + t2 + t3 + t4) * 0.2f;
            float z = fq0 * W6[0] + fq1 * W6[1] + smax * W6[2] + smean * W6[3]
                    + fq2 * W6[4] + fq3 * W6[5] + b1[0];
            prv = 1.f / (1.f + expf(-z));
        }
        prv += __shfl_down(prv, 16, 64);
        prv += __shfl_down(prv, 8, 64);
        prv += __shfl_down(prv, 4, 64);
        prv += __shfl_down(prv, 2, 64);
        prv += __shfl_down(prv, 1, 64);
        if (lane == 0) d_out[1 + (size_t)b * NSS + n] = prv * (1.f / 32.f);
    }
}

// ---------------- k_final: doc max + both BCEs + loss
__global__ __launch_bounds__(256) void k_final(const int* __restrict__ tsent,
                                               const int* __restrict__ tdoc,
                                               float* __restrict__ d_out) {
    const int tid = threadIdx.x;
    __shared__ float sh[256];
    __shared__ float docs[VB];
    if (tid < VB) {
        float m = -1e30f;
        for (int nn = 0; nn < NSS; ++nn) m = fmaxf(m, d_out[1 + tid * NSS + nn]);
        docs[tid] = m;
        d_out[1 + VB * NSS + tid] = m;
    }
    float s = 0.f;
    for (int i = tid; i < VB * NSS; i += 256) {
        float p = d_out[1 + i];
        p = fminf(fmaxf(p, 1e-7f), 1.f - 1e-7f);
        float t = (float)tsent[i];
        s += t * logf(p) + (1.f - t) * log1pf(-p);
    }
    sh[tid] = s;
    __syncthreads();
    for (int st = 128; st > 0; st >>= 1) {
        if (tid < st) sh[tid] += sh[tid + st];
        __syncthreads();
    }
    float ls = 0.f;
    if (tid == 0) ls = -sh[0] / (float)(VB * NSS);
    __syncthreads();
    float s2 = 0.f;
    if (tid < VB) {
        float p = fminf(fmaxf(docs[tid], 1e-7f), 1.f - 1e-7f);
        float t = (float)tdoc[tid];
        s2 = t * logf(p) + (1.f - t) * log1pf(-p);
    }
    sh[tid] = s2;
    __syncthreads();
    for (int st = 128; st > 0; st >>= 1) {
        if (tid < st) sh[tid] += sh[tid + st];
        __syncthreads();
    }
    if (tid == 0) {
        float ld = -sh[0] / (float)VB;
        d_out[0] = 0.5f * (ls + ld);
    }
}

extern "C" void kernel_launch(void* const* d_in, const int* in_sizes, int n_in,
                              void* d_out, int out_size, void* d_ws, size_t ws_size,
                              hipStream_t stream) {
    const int*   sentences = (const int*)d_in[0];
    const int*   question  = (const int*)d_in[1];
    const int*   tsent     = (const int*)d_in[2];
    const int*   tdoc      = (const int*)d_in[3];
    const float* embeds    = (const float*)d_in[4];
    const float* filters   = (const float*)d_in[5];
    const float* W6        = (const float*)d_in[6];
    const float* b1        = (const float*)d_in[7];
    float* out = (float*)d_out;

    float* ws = (float*)d_ws;
    float* q_inv  = ws;                         // 2,048 f
    float* qc_inv = ws + 2048;                  // 2,048 f
    unsigned short* qe_frag  = (unsigned short*)(ws + 4096);      // 655,360 sh (16B-aligned)
    unsigned short* qc_frag  = qe_frag + 655360;                  // 524,288 sh
    unsigned short* filt_frag = qc_frag + 524288;                 // 237,568 sh  (total ~2.85 MB)

    k_prep<<<VB + 116, 512, 0, stream>>>(question, embeds, filters,
                                         filt_frag, qe_frag, qc_frag, q_inv, qc_inv);
    k_sent<<<VB * NSS, 512, 0, stream>>>(sentences, question, embeds,
                                         filt_frag, qe_frag, qc_frag,
                                         q_inv, qc_inv, W6, b1, out);
    k_final<<<1, 256, 0, stream>>>(tsent, tdoc, out);
}

// Round 5
// 509.495 us; speedup vs baseline: 1.1510x; 1.1510x over previous
//
#include <hip/hip_runtime.h>
#include <math.h>

// Problem constants (Posit_Drmm_Modeler)
#define VB  64      // batch
#define NSS 50      // sentences per doc
#define LSS 60      // sentence length
#define LQQ 32      // question length
#define DD  300     // embedding dim
#define FF  256     // filters

#define SEST 312    // seb row stride (bf16): 312%8==0 -> 16B rows
#define SROWS 66    // rows 60..65 zero (conv A-frag overrun + M-pad)
#define SCST 264    // scb row stride (bf16)
#define SIMST 66    // sim row stride (fp32)
#define KKC 29      // conv K-steps (K=928 incl. stride pads; filter zeros neutralize)
#define KKI 10      // sim_ins K-steps (K=320, qe zero-padded)
#define KKS 8       // sim_sen K-steps (K=256)

typedef __attribute__((ext_vector_type(8))) short bfrag;   // 8 x bf16 (4 VGPRs)
typedef __attribute__((ext_vector_type(4))) float ffrag;   // 4 x f32 acc

__device__ __forceinline__ unsigned short f2bf(float v) {
    unsigned int x = __float_as_uint(v);
    x += 0x7fffu + ((x >> 16) & 1u);          // RNE
    return (unsigned short)(x >> 16);
}
__device__ __forceinline__ float bf2f(unsigned short u) {
    return __uint_as_float(((unsigned int)u) << 16);
}

// ---------------- k_fprep: filters fp32 -> bf16 MFMA B-fragment order (ushort4 vectorized)
// layout: [kk(29)][nt(16)][lane(64)][j(8)]; value = filt[f=nt*16+(lane&15)][k=kk*32+quad*8+j]
// with k -> (t=k/312, d=k%312), zero if t>=3 or d>=300. Also zeroes the completion counter.
__global__ __launch_bounds__(256) void k_fprep(const float* __restrict__ filters,
                                               unsigned short* __restrict__ filt_frag,
                                               int* __restrict__ ctr) {
    if (blockIdx.x == 0 && threadIdx.x == 0) *ctr = 0;
    int idx0 = (blockIdx.x * 256 + threadIdx.x) * 4;   // 232 blocks x 256 x 4 = 237,568 exact
    int j0 = idx0 & 7, ln = (idx0 >> 3) & 63, nt = (idx0 >> 9) & 15, kk = idx0 >> 13;
    int f = nt * 16 + (ln & 15);
    int k0 = kk * 32 + ((ln >> 4) << 3) + j0;
    int t = k0 / SEST, d0 = k0 - t * SEST;
    ushort4 h = {0, 0, 0, 0};
    if (t < 3 && d0 < DD) {
        float4 v = *(const float4*)(filters + f * 900 + t * DD + d0);
        h.x = f2bf(v.x); h.y = f2bf(v.y); h.z = f2bf(v.z); h.w = f2bf(v.w);
    }
    *(ushort4*)(filt_frag + idx0) = h;
}

// ---------------- k_qprep (merged, 512 thr): gather qe -> bf16 LDS (stride 312),
// q_inv + qe A-fragments, question-conv via MFMA reusing filt_frag, qc_inv + qc A-fragments.
__global__ __launch_bounds__(512) void k_qprep(const int* __restrict__ question,
                                               const float* __restrict__ embeds,
                                               const unsigned short* __restrict__ filt_frag,
                                               unsigned short* __restrict__ qe_frag,
                                               unsigned short* __restrict__ qc_frag,
                                               float* __restrict__ q_inv,
                                               float* __restrict__ qc_inv) {
    const int b = blockIdx.x, tid = threadIdx.x, lane = tid & 63, w = tid >> 6;
    const int quad = lane >> 4, m16 = lane & 15;
    __shared__ __align__(16) unsigned short qeb[34 * SEST];   // 21,216 B (rows 32..33 zero)
    __shared__ __align__(16) unsigned short qcb[LQQ * SCST];  // 16,896 B
    const int* qrow = question + b * LQQ;
    {   // zero col tails (rows 0..31, d 300..311) and rows 32..33
        ushort4 z4 = {0, 0, 0, 0};
        for (int i = tid; i < 96; i += 512) {
            int r = i / 3, c = 300 + (i - r * 3) * 4;
            *(ushort4*)(qeb + r * SEST + c) = z4;
        }
        for (int i = tid; i < 156; i += 512) {
            int r = i / 78, c = (i - r * 78) * 4;
            *(ushort4*)(qeb + (LQQ + r) * SEST + c) = z4;
        }
    }
    for (int i = tid; i < LQQ * 75; i += 512) {        // gather -> bf16 (ids direct from global)
        int r = i / 75, c = (i - r * 75) * 4;
        float4 v = *(const float4*)(embeds + (size_t)qrow[r] * DD + c);
        ushort4 h;
        h.x = f2bf(v.x); h.y = f2bf(v.y); h.z = f2bf(v.z); h.w = f2bf(v.w);
        *(ushort4*)(qeb + r * SEST + c) = h;
    }
    __syncthreads();
    if (tid < 256) {   // q_inv from bf16 (8 lanes/row), b128 reads
        int r = tid >> 3, part = tid & 7;
        float s = 0.f;
        #pragma unroll
        for (int it = 0; it < 5; ++it) {
            if (!(it == 4 && part == 7)) {
                int c = part * 8 + it * 64;
                uint4 u = *(const uint4*)(qeb + r * SEST + c);
                float a0 = bf2f((unsigned short)(u.x & 0xffff)), a1 = bf2f((unsigned short)(u.x >> 16));
                float a2 = bf2f((unsigned short)(u.y & 0xffff)), a3 = bf2f((unsigned short)(u.y >> 16));
                float a4 = bf2f((unsigned short)(u.z & 0xffff)), a5 = bf2f((unsigned short)(u.z >> 16));
                float a6 = bf2f((unsigned short)(u.w & 0xffff)), a7 = bf2f((unsigned short)(u.w >> 16));
                s += a0 * a0 + a1 * a1 + a2 * a2 + a3 * a3 + a4 * a4 + a5 * a5 + a6 * a6 + a7 * a7;
            }
        }
        s += __shfl_down(s, 4, 64);
        s += __shfl_down(s, 2, 64);
        s += __shfl_down(s, 1, 64);
        if (part == 0) q_inv[b * LQQ + r] = 1.f / sqrtf(s);
    }
    // qe A-fragments: [kk(10)][mt(2)][lane(64)][j(8)] per b -- uint4 vectorized (8 bf16 per store)
    for (int i8 = tid; i8 < KKI * 2 * 64; i8 += 512) {
        int ln = i8 & 63, mt = (i8 >> 6) & 1, kk = i8 >> 7;
        int q = mt * 16 + (ln & 15);
        int k0 = kk * 32 + ((ln >> 4) << 3);
        uint4 v = {0, 0, 0, 0};
        if (k0 < SEST) v = *(const uint4*)(qeb + q * SEST + k0);   // tails 300..311 are zero
        *(uint4*)(qe_frag + (size_t)b * (KKI * 2 * 512) + (size_t)i8 * 8) = v;
    }
    // ===== question conv GEMM: C[q=32][f=256] = qeb-window[32x928] x filt[928x256] =====
    // 8 waves: wave w owns M-tile (w&1), N-tiles (w>>1)*4 .. +3; depth-1 B prefetch
    const int mtq = w & 1, w4 = (w >> 1) * 4;
    ffrag acc[4];
    #pragma unroll
    for (int i = 0; i < 4; ++i) acc[i] = (ffrag)0.f;
    {
        const bfrag* fF = (const bfrag*)filt_frag;
        bfrag bb[4], nb[4];
        #pragma unroll
        for (int i = 0; i < 4; ++i) bb[i] = fF[(w4 + i) * 64 + lane];
        for (int kk = 0; kk < KKC; ++kk) {
            if (kk + 1 < KKC) {
                #pragma unroll
                for (int i = 0; i < 4; ++i) nb[i] = fF[((kk + 1) * 16 + w4 + i) * 64 + lane];
            }
            const int kb = kk * 32 + quad * 8;
            bfrag a0 = *(const bfrag*)(qeb + (mtq * 16 + m16) * SEST + kb);
            #pragma unroll
            for (int i = 0; i < 4; ++i)
                acc[i] = __builtin_amdgcn_mfma_f32_16x16x32_bf16(a0, bb[i], acc[i], 0, 0, 0);
            #pragma unroll
            for (int i = 0; i < 4; ++i) bb[i] = nb[i];
        }
    }
    // C -> qcb bf16 [q][f]
    #pragma unroll
    for (int i = 0; i < 4; ++i) {
        int f = (w4 + i) * 16 + m16;
        #pragma unroll
        for (int r = 0; r < 4; ++r) {
            int q = mtq * 16 + quad * 4 + r;
            qcb[q * SCST + f] = f2bf(acc[i][r]);
        }
    }
    __syncthreads();
    if (tid < 256) {   // qc_inv from bf16, b128 reads (FF=256 = 4 full iters)
        int r = tid >> 3, part = tid & 7;
        float s = 0.f;
        #pragma unroll
        for (int it = 0; it < 4; ++it) {
            int c = part * 8 + it * 64;
            uint4 u = *(const uint4*)(qcb + r * SCST + c);
            float a0 = bf2f((unsigned short)(u.x & 0xffff)), a1 = bf2f((unsigned short)(u.x >> 16));
            float a2 = bf2f((unsigned short)(u.y & 0xffff)), a3 = bf2f((unsigned short)(u.y >> 16));
            float a4 = bf2f((unsigned short)(u.z & 0xffff)), a5 = bf2f((unsigned short)(u.z >> 16));
            float a6 = bf2f((unsigned short)(u.w & 0xffff)), a7 = bf2f((unsigned short)(u.w >> 16));
            s += a0 * a0 + a1 * a1 + a2 * a2 + a3 * a3 + a4 * a4 + a5 * a5 + a6 * a6 + a7 * a7;
        }
        s += __shfl_down(s, 4, 64);
        s += __shfl_down(s, 2, 64);
        s += __shfl_down(s, 1, 64);
        if (part == 0) qc_inv[b * LQQ + r] = 1.f / sqrtf(s);
    }
    // qc A-fragments: [kk(8)][mt(2)][lane(64)][j(8)] per b -- uint4 vectorized
    for (int i8 = tid; i8 < KKS * 2 * 64; i8 += 512) {
        int ln = i8 & 63, mt = (i8 >> 6) & 1, kk = i8 >> 7;
        int q = mt * 16 + (ln & 15);
        int k0 = kk * 32 + ((ln >> 4) << 3);               // <= 248, in-row
        *(uint4*)(qc_frag + (size_t)b * (KKS * 2 * 512) + (size_t)i8 * 8) =
            *(const uint4*)(qcb + q * SCST + k0);
    }
}

// one conv K-step: 4 A-frags from LDS + 8 MFMA with prefetched B regs
#define CONV_STEP(KKV, BB0, BB1) do {                                              \
    const int kb_ = (KKV) * 32 + quad * 8;                                         \
    bfrag a0_ = *(const bfrag*)(seb + (m16) * SEST + kb_);                         \
    bfrag a1_ = *(const bfrag*)(seb + (16 + m16) * SEST + kb_);                    \
    bfrag a2_ = *(const bfrag*)(seb + (32 + m16) * SEST + kb_);                    \
    bfrag a3_ = *(const bfrag*)(seb + (48 + m16) * SEST + kb_);                    \
    __builtin_amdgcn_s_setprio(1);                                                 \
    acc[0][0] = __builtin_amdgcn_mfma_f32_16x16x32_bf16(a0_, BB0, acc[0][0], 0, 0, 0); \
    acc[0][1] = __builtin_amdgcn_mfma_f32_16x16x32_bf16(a0_, BB1, acc[0][1], 0, 0, 0); \
    acc[1][0] = __builtin_amdgcn_mfma_f32_16x16x32_bf16(a1_, BB0, acc[1][0], 0, 0, 0); \
    acc[1][1] = __builtin_amdgcn_mfma_f32_16x16x32_bf16(a1_, BB1, acc[1][1], 0, 0, 0); \
    acc[2][0] = __builtin_amdgcn_mfma_f32_16x16x32_bf16(a2_, BB0, acc[2][0], 0, 0, 0); \
    acc[2][1] = __builtin_amdgcn_mfma_f32_16x16x32_bf16(a2_, BB1, acc[2][1], 0, 0, 0); \
    acc[3][0] = __builtin_amdgcn_mfma_f32_16x16x32_bf16(a3_, BB0, acc[3][0], 0, 0, 0); \
    acc[3][1] = __builtin_amdgcn_mfma_f32_16x16x32_bf16(a3_, BB1, acc[3][1], 0, 0, 0); \
    __builtin_amdgcn_s_setprio(0);                                                 \
} while (0)

// ---------------- k_sent: fused per-(b,n), 512 threads / 8 waves, 3 blocks/CU
// Last-arriving block's wave 0 performs the final doc-max + BCE reduction (fused k_final).
__global__ __launch_bounds__(512, 6) void k_sent(
    const int* __restrict__ sentences, const int* __restrict__ question,
    const float* __restrict__ embeds,
    const unsigned short* __restrict__ filt_frag,
    const unsigned short* __restrict__ qe_frag,
    const unsigned short* __restrict__ qc_frag,
    const float* __restrict__ q_inv, const float* __restrict__ qc_inv,
    const float* __restrict__ W6, const float* __restrict__ b1,
    const int* __restrict__ tsent, const int* __restrict__ tdoc,
    int* __restrict__ ctr,
    float* __restrict__ d_out) {
    const int blk = blockIdx.x;
    const int b = blk / NSS, n = blk - b * NSS;
    const int tid = threadIdx.x, lane = tid & 63, w = tid >> 6;     // w in [0,8)
    const int quad = lane >> 4, m16 = lane & 15;
    const int w2 = w * 2;

    __shared__ __align__(16) unsigned short seb[SROWS * SEST]; // 41,184 B; overlaid by scb after conv
    __shared__ __align__(16) float sim[LQQ * SIMST];           // 8,448 B
    __shared__ float sinv[64], scninv[64];
    __shared__ int sid[64];
    __shared__ int qid[LQQ];
    __shared__ float qm[LQQ], qiv[LQQ], qciv[LQQ];
    __shared__ float featq[LQQ][4];
    __shared__ float pr[LQQ];
    unsigned short* scb = seb;   // overlay: conv output [l][f] bf16 (60+4 zero rows x 264)

    // early prefetch of first conv B-fragments (independent of LDS)
    const bfrag* fF = (const bfrag*)filt_frag;
    bfrag b0a = fF[(w2) * 64 + lane];
    bfrag b0b = fF[(w2 + 1) * 64 + lane];

    const int* srow = sentences + ((size_t)b * NSS + n) * LSS;
    if (tid < 64) sid[tid] = (tid < LSS) ? srow[tid] : 0;
    if (tid < LQQ) {
        int qi = question[b * LQQ + tid];
        qid[tid] = qi; qm[tid] = qi > 0 ? 1.f : 0.f;
        qiv[tid] = q_inv[b * LQQ + tid]; qciv[tid] = qc_inv[b * LQQ + tid];
    }
    // zero seb row tails (d 300..311) and rows 60..65 (disjoint from gather region -> no barrier)
    {
        ushort4 z4 = {0, 0, 0, 0};
        for (int i = tid; i < 180; i += 512) {
            int r = i / 3, c = 300 + (i - r * 3) * 4;
            *(ushort4*)(seb + r * SEST + c) = z4;
        }
        for (int i = tid; i < 468; i += 512) {
            int r = i / 78, c = (i - r * 78) * 4;
            *(ushort4*)(seb + (60 + r) * SEST + c) = z4;
        }
    }
    // gather sentence embeddings -> bf16 LDS (token ids direct from global; L1-hot)
    for (int i = tid; i < LSS * 75; i += 512) {
        int r = i / 75, c = (i - r * 75) * 4;
        float4 v = *(const float4*)(embeds + (size_t)srow[r] * DD + c);
        ushort4 h;
        h.x = f2bf(v.x); h.y = f2bf(v.y); h.z = f2bf(v.z); h.w = f2bf(v.w);
        *(ushort4*)(seb + r * SEST + c) = h;
    }
    __syncthreads();
    // row inv-norms from bf16 (8 lanes per row, 480 threads), b128 reads
    if (tid < 480) {
        int r = tid >> 3, part = tid & 7;
        float s = 0.f;
        #pragma unroll
        for (int it = 0; it < 5; ++it) {
            if (!(it == 4 && part == 7)) {       // c=312 would cross into next row
                int c = part * 8 + it * 64;      // tails 300..311 are zero -> safe
                uint4 u = *(const uint4*)(seb + r * SEST + c);
                float a0 = bf2f((unsigned short)(u.x & 0xffff)), a1 = bf2f((unsigned short)(u.x >> 16));
                float a2 = bf2f((unsigned short)(u.y & 0xffff)), a3 = bf2f((unsigned short)(u.y >> 16));
                float a4 = bf2f((unsigned short)(u.z & 0xffff)), a5 = bf2f((unsigned short)(u.z >> 16));
                float a6 = bf2f((unsigned short)(u.w & 0xffff)), a7 = bf2f((unsigned short)(u.w >> 16));
                s += a0 * a0 + a1 * a1 + a2 * a2 + a3 * a3 + a4 * a4 + a5 * a5 + a6 * a6 + a7 * a7;
            }
        }
        s += __shfl_down(s, 4, 64);
        s += __shfl_down(s, 2, 64);
        s += __shfl_down(s, 1, 64);
        if (part == 0) sinv[r] = 1.f / sqrtf(s);
    }
    if (tid >= 480 && tid < 484) sinv[60 + tid - 480] = 0.f;
    __syncthreads();

    // ======== conv GEMM: C[l=64][f=256] = seb-window[64x928] x filt[928x256] ========
    // wave w owns N-tiles {2w, 2w+1}, all 4 M-tiles. Software-pipelined B prefetch (unroll-2).
    ffrag acc[4][2];
    #pragma unroll
    for (int mt = 0; mt < 4; ++mt)
        #pragma unroll
        for (int i = 0; i < 2; ++i) acc[mt][i] = (ffrag)0.f;
    {
        bfrag b1a, b1b;
        for (int kk = 0; kk + 2 <= KKC; kk += 2) {
            b1a = fF[((kk + 1) * 16 + w2) * 64 + lane];
            b1b = fF[((kk + 1) * 16 + w2 + 1) * 64 + lane];
            CONV_STEP(kk, b0a, b0b);
            if (kk + 2 < KKC) {
                b0a = fF[((kk + 2) * 16 + w2) * 64 + lane];
                b0b = fF[((kk + 2) * 16 + w2 + 1) * 64 + lane];
            }
            CONV_STEP(kk + 1, b1a, b1b);
        }
        CONV_STEP(KKC - 1, b0a, b0b);   // kk=28, loaded during kk=26 pair
    }
    // ======== sim_ins GEMM: C[q=32][l=64] = qe[32x320] x seb^T; wave w owns 1 tile ========
    {
        const int mt = w >> 2, nt = w & 3;
        const bfrag* qF = (const bfrag*)qe_frag + ((size_t)b * KKI * 2 + mt) * 64 + lane;
        const unsigned short* sebr = seb + (nt * 16 + m16) * SEST + quad * 8;
        ffrag c0 = (ffrag)0.f;
        bfrag aq0 = qF[0];
        for (int kk = 0; kk < KKI; kk += 2) {
            bfrag aq1 = qF[(kk + 1) * 128];
            bfrag bL0 = *(const bfrag*)(sebr + kk * 32);
            c0 = __builtin_amdgcn_mfma_f32_16x16x32_bf16(aq0, bL0, c0, 0, 0, 0);
            if (kk + 2 < KKI) aq0 = qF[(kk + 2) * 128];
            bfrag bL1 = *(const bfrag*)(sebr + (kk + 1) * 32);
            c0 = __builtin_amdgcn_mfma_f32_16x16x32_bf16(aq1, bL1, c0, 0, 0, 0);
        }
        const int l_ = nt * 16 + m16;
        const float sm = sinv[l_] * (sid[l_] > 0 ? 1.f : 0.f);
        #pragma unroll
        for (int r = 0; r < 4; ++r) {
            int q = mt * 16 + quad * 4 + r;
            sim[q * SIMST + l_] = c0[r] * (qiv[q] * qm[q]) * sm;
        }
    }
    __syncthreads();   // all seb reads done; sim_ins visible

    // ======== conv C -> scb bf16 [l][f] (overlays seb) + zero rows 60..63 + pool_ins ========
    if (tid < 256) {
        ushort4 z4 = {0, 0, 0, 0};
        int r4 = 60 + (tid >> 6), c4 = (tid & 63) * 4;
        *(ushort4*)(scb + r4 * SCST + c4) = z4;
    }
    #pragma unroll
    for (int mt = 0; mt < 4; ++mt)
        #pragma unroll
        for (int i = 0; i < 2; ++i) {
            int f = (w2 + i) * 16 + m16;
            #pragma unroll
            for (int r = 0; r < 4; ++r) {
                int l = mt * 16 + quad * 4 + r;
                scb[l * SCST + f] = f2bf(acc[mt][i][r]);
            }
        }
    if (tid < LQQ) {   // pool_ins + exact-match channel (integer equality, incl pad==pad, unmasked)
        int q = tid;
        float t0 = -1e30f, t1 = -1e30f, t2 = -1e30f, t3 = -1e30f, t4 = -1e30f;
        for (int l = 0; l < LSS; ++l) {
            float v = sim[q * SIMST + l];
            if (v > t4) {
                if (v > t0)      { t4 = t3; t3 = t2; t2 = t1; t1 = t0; t0 = v; }
                else if (v > t1) { t4 = t3; t3 = t2; t2 = t1; t1 = v; }
                else if (v > t2) { t4 = t3; t3 = t2; t2 = v; }
                else if (v > t3) { t4 = t3; t3 = v; }
                else               t4 = v;
            }
        }
        featq[q][0] = t0;
        featq[q][1] = (t0 + t1 + t2 + t3 + t4) * 0.2f;
        int qi = qid[q], c = 0;
        for (int l = 0; l < LSS; ++l) c += (sid[l] == qi) ? 1 : 0;
        featq[q][2] = c > 0 ? 1.f : 0.f;
        featq[q][3] = (float)(c < 5 ? c : 5) * 0.2f;
    }
    __syncthreads();
    // scb row inv-norms (8 lanes per row, 480 threads), b128 reads (FF=256 = 4 full iters)
    if (tid < 480) {
        int r = tid >> 3, part = tid & 7;
        float s = 0.f;
        #pragma unroll
        for (int it = 0; it < 4; ++it) {
            int c = part * 8 + it * 64;
            uint4 u = *(const uint4*)(scb + r * SCST + c);
            float a0 = bf2f((unsigned short)(u.x & 0xffff)), a1 = bf2f((unsigned short)(u.x >> 16));
            float a2 = bf2f((unsigned short)(u.y & 0xffff)), a3 = bf2f((unsigned short)(u.y >> 16));
            float a4 = bf2f((unsigned short)(u.z & 0xffff)), a5 = bf2f((unsigned short)(u.z >> 16));
            float a6 = bf2f((unsigned short)(u.w & 0xffff)), a7 = bf2f((unsigned short)(u.w >> 16));
            s += a0 * a0 + a1 * a1 + a2 * a2 + a3 * a3 + a4 * a4 + a5 * a5 + a6 * a6 + a7 * a7;
        }
        s += __shfl_down(s, 4, 64);
        s += __shfl_down(s, 2, 64);
        s += __shfl_down(s, 1, 64);
        if (part == 0) scninv[r] = 1.f / sqrtf(s);
    }
    if (tid >= 480 && tid < 484) scninv[60 + tid - 480] = 0.f;
    __syncthreads();
    // ======== sim_sen GEMM: C[q=32][l=64] = qc[32x256] x scb^T; wave w owns 1 tile ========
    {
        const int mt = w >> 2, nt = w & 3;
        const bfrag* qF = (const bfrag*)qc_frag + ((size_t)b * KKS * 2 + mt) * 64 + lane;
        const unsigned short* scbr = scb + (nt * 16 + m16) * SCST + quad * 8;
        ffrag c0 = (ffrag)0.f;
        bfrag aq0 = qF[0];
        for (int kk = 0; kk < KKS; kk += 2) {
            bfrag aq1 = qF[(kk + 1) * 128];
            bfrag bL0 = *(const bfrag*)(scbr + kk * 32);
            c0 = __builtin_amdgcn_mfma_f32_16x16x32_bf16(aq0, bL0, c0, 0, 0, 0);
            if (kk + 2 < KKS) aq0 = qF[(kk + 2) * 128];
            bfrag bL1 = *(const bfrag*)(scbr + (kk + 1) * 32);
            c0 = __builtin_amdgcn_mfma_f32_16x16x32_bf16(aq1, bL1, c0, 0, 0, 0);
        }
        const int l_ = nt * 16 + m16;
        const float sm = scninv[l_] * (sid[l_] > 0 ? 1.f : 0.f);
        #pragma unroll
        for (int r = 0; r < 4; ++r) {
            int q = mt * 16 + quad * 4 + r;
            sim[q * SIMST + l_] = c0[r] * (qciv[q] * qm[q]) * sm;
        }
    }
    __syncthreads();
    if (tid < LQQ) {   // pool_sen + linear + sigmoid
        int q = tid;
        float t0 = -1e30f, t1 = -1e30f, t2 = -1e30f, t3 = -1e30f, t4 = -1e30f;
        for (int l = 0; l < LSS; ++l) {
            float v = sim[q * SIMST + l];
            if (v > t4) {
                if (v > t0)      { t4 = t3; t3 = t2; t2 = t1; t1 = t0; t0 = v; }
                else if (v > t1) { t4 = t3; t3 = t2; t2 = t1; t1 = v; }
                else if (v > t2) { t4 = t3; t3 = t2; t2 = v; }
                else if (v > t3) { t4 = t3; t3 = v; }
                else               t4 = v;
            }
        }
        float smax = t0, smean = (t0 + t1 + t2 + t3 + t4) * 0.2f;
        float z = featq[q][0] * W6[0] + featq[q][1] * W6[1] + smax * W6[2] + smean * W6[3]
                + featq[q][2] * W6[4] + featq[q][3] * W6[5] + b1[0];
        pr[q] = 1.f / (1.f + expf(-z));
    }
    __syncthreads();
    if (w == 0) {
        float s = (lane < LQQ) ? pr[lane] : 0.f;
        s += __shfl_down(s, 16, 64);
        s += __shfl_down(s, 8, 64);
        s += __shfl_down(s, 4, 64);
        s += __shfl_down(s, 2, 64);
        s += __shfl_down(s, 1, 64);
        if (lane == 0) d_out[1 + (size_t)b * NSS + n] = s * (1.f / 32.f);

        // ---- fused k_final: last-arriving block's wave 0 does doc-max + both BCEs ----
        int last = 0;
        if (lane == 0) {
            __threadfence();
            int old = __hip_atomic_fetch_add(ctr, 1, __ATOMIC_ACQ_REL, __HIP_MEMORY_SCOPE_AGENT);
            last = (old == VB * NSS - 1) ? 1 : 0;
        }
        last = __shfl(last, 0, 64);
        if (last) {
            // doc max: lane = doc index (VB == 64 lanes)
            float m = -1e30f;
            for (int nn = 0; nn < NSS; ++nn) {
                float v = __hip_atomic_load(d_out + 1 + lane * NSS + nn,
                                            __ATOMIC_RELAXED, __HIP_MEMORY_SCOPE_AGENT);
                m = fmaxf(m, v);
            }
            d_out[1 + VB * NSS + lane] = m;
            // sentence BCE sum
            float ssent = 0.f;
            for (int i = lane; i < VB * NSS; i += 64) {
                float p = __hip_atomic_load(d_out + 1 + i,
                                            __ATOMIC_RELAXED, __HIP_MEMORY_SCOPE_AGENT);
                p = fminf(fmaxf(p, 1e-7f), 1.f - 1e-7f);
                float t = (float)tsent[i];
                ssent += t * logf(p) + (1.f - t) * log1pf(-p);
            }
            #pragma unroll
            for (int off = 32; off > 0; off >>= 1) ssent += __shfl_down(ssent, off, 64);
            // doc BCE (each lane owns its doc's max)
            float p2 = fminf(fmaxf(m, 1e-7f), 1.f - 1e-7f);
            float t2 = (float)tdoc[lane];
            float sdoc = t2 * logf(p2) + (1.f - t2) * log1pf(-p2);
            #pragma unroll
            for (int off = 32; off > 0; off >>= 1) sdoc += __shfl_down(sdoc, off, 64);
            if (lane == 0) {
                float ls = -ssent / (float)(VB * NSS);
                float ld = -sdoc / (float)VB;
                d_out[0] = 0.5f * (ls + ld);
            }
        }
    }
}

extern "C" void kernel_launch(void* const* d_in, const int* in_sizes, int n_in,
                              void* d_out, int out_size, void* d_ws, size_t ws_size,
                              hipStream_t stream) {
    const int*   sentences = (const int*)d_in[0];
    const int*   question  = (const int*)d_in[1];
    const int*   tsent     = (const int*)d_in[2];
    const int*   tdoc      = (const int*)d_in[3];
    const float* embeds    = (const float*)d_in[4];
    const float* filters   = (const float*)d_in[5];
    const float* W6        = (const float*)d_in[6];
    const float* b1        = (const float*)d_in[7];
    float* out = (float*)d_out;

    float* ws = (float*)d_ws;
    float* q_inv  = ws;                         // 2,048 f
    float* qc_inv = ws + 2048;                  // 2,048 f
    unsigned short* qe_frag  = (unsigned short*)(ws + 4096);      // 655,360 sh (16B-aligned)
    unsigned short* qc_frag  = qe_frag + 655360;                  // 524,288 sh
    unsigned short* filt_frag = qc_frag + 524288;                 // 237,568 sh
    int* ctr = (int*)(filt_frag + 237568);                        // completion counter

    k_fprep<<<232, 256, 0, stream>>>(filters, filt_frag, ctr);
    k_qprep<<<VB, 512, 0, stream>>>(question, embeds, filt_frag, qe_frag, qc_frag, q_inv, qc_inv);
    k_sent<<<VB * NSS, 512, 0, stream>>>(sentences, question, embeds,
                                         filt_frag, qe_frag, qc_frag,
                                         q_inv, qc_inv, W6, b1,
                                         tsent, tdoc, ctr, out);
}

// Round 6
// 398.915 us; speedup vs baseline: 1.4700x; 1.2772x over previous
//
#include <hip/hip_runtime.h>
#include <math.h>

// Problem constants (Posit_Drmm_Modeler)
#define VB  64      // batch
#define NSS 50      // sentences per doc
#define LSS 60      // sentence length
#define LQQ 32      // question length
#define DD  300     // embedding dim
#define FF  256     // filters

#define SEST 312    // seb row stride (bf16): 312%8==0 -> 16B rows
#define SROWS 66    // rows 60..65 zero (conv A-frag overrun + M-pad)
#define SCST 264    // scb row stride (bf16)
#define SIMST 66    // sim row stride (fp32)
#define KKC 29      // conv K-steps (K=928 incl. stride pads; filter zeros neutralize)
#define KKI 10      // sim_ins K-steps (K=320, qe zero-padded)
#define KKS 8       // sim_sen K-steps (K=256)

typedef __attribute__((ext_vector_type(8))) short bfrag;   // 8 x bf16 (4 VGPRs)
typedef __attribute__((ext_vector_type(4))) float ffrag;   // 4 x f32 acc

__device__ __forceinline__ unsigned short f2bf(float v) {
    unsigned int x = __float_as_uint(v);
    x += 0x7fffu + ((x >> 16) & 1u);          // RNE
    return (unsigned short)(x >> 16);
}
__device__ __forceinline__ float bf2f(unsigned short u) {
    return __uint_as_float(((unsigned int)u) << 16);
}

// ---------------- k_fprep: filters fp32 -> bf16 MFMA B-fragment order (ushort4 vectorized)
// layout: [kk(29)][nt(16)][lane(64)][j(8)]; value = filt[f=nt*16+(lane&15)][k=kk*32+quad*8+j]
// with k -> (t=k/312, d=k%312), zero if t>=3 or d>=300.
__global__ __launch_bounds__(256) void k_fprep(const float* __restrict__ filters,
                                               unsigned short* __restrict__ filt_frag) {
    int idx0 = (blockIdx.x * 256 + threadIdx.x) * 4;   // 232 blocks x 256 x 4 = 237,568 exact
    int j0 = idx0 & 7, ln = (idx0 >> 3) & 63, nt = (idx0 >> 9) & 15, kk = idx0 >> 13;
    int f = nt * 16 + (ln & 15);
    int k0 = kk * 32 + ((ln >> 4) << 3) + j0;
    int t = k0 / SEST, d0 = k0 - t * SEST;
    ushort4 h = {0, 0, 0, 0};
    if (t < 3 && d0 < DD) {
        float4 v = *(const float4*)(filters + f * 900 + t * DD + d0);
        h.x = f2bf(v.x); h.y = f2bf(v.y); h.z = f2bf(v.z); h.w = f2bf(v.w);
    }
    *(ushort4*)(filt_frag + idx0) = h;
}

// ---------------- k_qprep (merged, 512 thr): gather qe -> bf16 LDS (stride 312),
// q_inv + qe A-fragments, question-conv via MFMA reusing filt_frag, qc_inv + qc A-fragments.
__global__ __launch_bounds__(512) void k_qprep(const int* __restrict__ question,
                                               const float* __restrict__ embeds,
                                               const unsigned short* __restrict__ filt_frag,
                                               unsigned short* __restrict__ qe_frag,
                                               unsigned short* __restrict__ qc_frag,
                                               float* __restrict__ q_inv,
                                               float* __restrict__ qc_inv) {
    const int b = blockIdx.x, tid = threadIdx.x, lane = tid & 63, w = tid >> 6;
    const int quad = lane >> 4, m16 = lane & 15;
    __shared__ __align__(16) unsigned short qeb[34 * SEST];   // 21,216 B (rows 32..33 zero)
    __shared__ __align__(16) unsigned short qcb[LQQ * SCST];  // 16,896 B
    const int* qrow = question + b * LQQ;
    {   // zero col tails (rows 0..31, d 300..311) and rows 32..33
        ushort4 z4 = {0, 0, 0, 0};
        for (int i = tid; i < 96; i += 512) {
            int r = i / 3, c = 300 + (i - r * 3) * 4;
            *(ushort4*)(qeb + r * SEST + c) = z4;
        }
        for (int i = tid; i < 156; i += 512) {
            int r = i / 78, c = (i - r * 78) * 4;
            *(ushort4*)(qeb + (LQQ + r) * SEST + c) = z4;
        }
    }
    for (int i = tid; i < LQQ * 75; i += 512) {        // gather -> bf16 (ids direct from global)
        int r = i / 75, c = (i - r * 75) * 4;
        float4 v = *(const float4*)(embeds + (size_t)qrow[r] * DD + c);
        ushort4 h;
        h.x = f2bf(v.x); h.y = f2bf(v.y); h.z = f2bf(v.z); h.w = f2bf(v.w);
        *(ushort4*)(qeb + r * SEST + c) = h;
    }
    __syncthreads();
    if (tid < 256) {   // q_inv from bf16 (8 lanes/row), b128 reads
        int r = tid >> 3, part = tid & 7;
        float s = 0.f;
        #pragma unroll
        for (int it = 0; it < 5; ++it) {
            if (!(it == 4 && part == 7)) {
                int c = part * 8 + it * 64;
                uint4 u = *(const uint4*)(qeb + r * SEST + c);
                float a0 = bf2f((unsigned short)(u.x & 0xffff)), a1 = bf2f((unsigned short)(u.x >> 16));
                float a2 = bf2f((unsigned short)(u.y & 0xffff)), a3 = bf2f((unsigned short)(u.y >> 16));
                float a4 = bf2f((unsigned short)(u.z & 0xffff)), a5 = bf2f((unsigned short)(u.z >> 16));
                float a6 = bf2f((unsigned short)(u.w & 0xffff)), a7 = bf2f((unsigned short)(u.w >> 16));
                s += a0 * a0 + a1 * a1 + a2 * a2 + a3 * a3 + a4 * a4 + a5 * a5 + a6 * a6 + a7 * a7;
            }
        }
        s += __shfl_down(s, 4, 64);
        s += __shfl_down(s, 2, 64);
        s += __shfl_down(s, 1, 64);
        if (part == 0) q_inv[b * LQQ + r] = 1.f / sqrtf(s);
    }
    // qe A-fragments: [kk(10)][mt(2)][lane(64)][j(8)] per b -- uint4 vectorized (8 bf16 per store)
    for (int i8 = tid; i8 < KKI * 2 * 64; i8 += 512) {
        int ln = i8 & 63, mt = (i8 >> 6) & 1, kk = i8 >> 7;
        int q = mt * 16 + (ln & 15);
        int k0 = kk * 32 + ((ln >> 4) << 3);
        uint4 v = {0, 0, 0, 0};
        if (k0 < SEST) v = *(const uint4*)(qeb + q * SEST + k0);   // tails 300..311 are zero
        *(uint4*)(qe_frag + (size_t)b * (KKI * 2 * 512) + (size_t)i8 * 8) = v;
    }
    // ===== question conv GEMM: C[q=32][f=256] = qeb-window[32x928] x filt[928x256] =====
    // 8 waves: wave w owns M-tile (w&1), N-tiles (w>>1)*4 .. +3; depth-1 B prefetch
    const int mtq = w & 1, w4 = (w >> 1) * 4;
    ffrag acc[4];
    #pragma unroll
    for (int i = 0; i < 4; ++i) acc[i] = (ffrag)0.f;
    {
        const bfrag* fF = (const bfrag*)filt_frag;
        bfrag bb[4], nb[4];
        #pragma unroll
        for (int i = 0; i < 4; ++i) bb[i] = fF[(w4 + i) * 64 + lane];
        for (int kk = 0; kk < KKC; ++kk) {
            if (kk + 1 < KKC) {
                #pragma unroll
                for (int i = 0; i < 4; ++i) nb[i] = fF[((kk + 1) * 16 + w4 + i) * 64 + lane];
            }
            const int kb = kk * 32 + quad * 8;
            bfrag a0 = *(const bfrag*)(qeb + (mtq * 16 + m16) * SEST + kb);
            #pragma unroll
            for (int i = 0; i < 4; ++i)
                acc[i] = __builtin_amdgcn_mfma_f32_16x16x32_bf16(a0, bb[i], acc[i], 0, 0, 0);
            #pragma unroll
            for (int i = 0; i < 4; ++i) bb[i] = nb[i];
        }
    }
    // C -> qcb bf16 [q][f]
    #pragma unroll
    for (int i = 0; i < 4; ++i) {
        int f = (w4 + i) * 16 + m16;
        #pragma unroll
        for (int r = 0; r < 4; ++r) {
            int q = mtq * 16 + quad * 4 + r;
            qcb[q * SCST + f] = f2bf(acc[i][r]);
        }
    }
    __syncthreads();
    if (tid < 256) {   // qc_inv from bf16, b128 reads (FF=256 = 4 full iters)
        int r = tid >> 3, part = tid & 7;
        float s = 0.f;
        #pragma unroll
        for (int it = 0; it < 4; ++it) {
            int c = part * 8 + it * 64;
            uint4 u = *(const uint4*)(qcb + r * SCST + c);
            float a0 = bf2f((unsigned short)(u.x & 0xffff)), a1 = bf2f((unsigned short)(u.x >> 16));
            float a2 = bf2f((unsigned short)(u.y & 0xffff)), a3 = bf2f((unsigned short)(u.y >> 16));
            float a4 = bf2f((unsigned short)(u.z & 0xffff)), a5 = bf2f((unsigned short)(u.z >> 16));
            float a6 = bf2f((unsigned short)(u.w & 0xffff)), a7 = bf2f((unsigned short)(u.w >> 16));
            s += a0 * a0 + a1 * a1 + a2 * a2 + a3 * a3 + a4 * a4 + a5 * a5 + a6 * a6 + a7 * a7;
        }
        s += __shfl_down(s, 4, 64);
        s += __shfl_down(s, 2, 64);
        s += __shfl_down(s, 1, 64);
        if (part == 0) qc_inv[b * LQQ + r] = 1.f / sqrtf(s);
    }
    // qc A-fragments: [kk(8)][mt(2)][lane(64)][j(8)] per b -- uint4 vectorized
    for (int i8 = tid; i8 < KKS * 2 * 64; i8 += 512) {
        int ln = i8 & 63, mt = (i8 >> 6) & 1, kk = i8 >> 7;
        int q = mt * 16 + (ln & 15);
        int k0 = kk * 32 + ((ln >> 4) << 3);               // <= 248, in-row
        *(uint4*)(qc_frag + (size_t)b * (KKS * 2 * 512) + (size_t)i8 * 8) =
            *(const uint4*)(qcb + q * SCST + k0);
    }
}

// one conv K-step: 4 A-frags from LDS + 8 MFMA with prefetched B regs
#define CONV_STEP(KKV, BB0, BB1) do {                                              \
    const int kb_ = (KKV) * 32 + quad * 8;                                         \
    bfrag a0_ = *(const bfrag*)(seb + (m16) * SEST + kb_);                         \
    bfrag a1_ = *(const bfrag*)(seb + (16 + m16) * SEST + kb_);                    \
    bfrag a2_ = *(const bfrag*)(seb + (32 + m16) * SEST + kb_);                    \
    bfrag a3_ = *(const bfrag*)(seb + (48 + m16) * SEST + kb_);                    \
    __builtin_amdgcn_s_setprio(1);                                                 \
    acc[0][0] = __builtin_amdgcn_mfma_f32_16x16x32_bf16(a0_, BB0, acc[0][0], 0, 0, 0); \
    acc[0][1] = __builtin_amdgcn_mfma_f32_16x16x32_bf16(a0_, BB1, acc[0][1], 0, 0, 0); \
    acc[1][0] = __builtin_amdgcn_mfma_f32_16x16x32_bf16(a1_, BB0, acc[1][0], 0, 0, 0); \
    acc[1][1] = __builtin_amdgcn_mfma_f32_16x16x32_bf16(a1_, BB1, acc[1][1], 0, 0, 0); \
    acc[2][0] = __builtin_amdgcn_mfma_f32_16x16x32_bf16(a2_, BB0, acc[2][0], 0, 0, 0); \
    acc[2][1] = __builtin_amdgcn_mfma_f32_16x16x32_bf16(a2_, BB1, acc[2][1], 0, 0, 0); \
    acc[3][0] = __builtin_amdgcn_mfma_f32_16x16x32_bf16(a3_, BB0, acc[3][0], 0, 0, 0); \
    acc[3][1] = __builtin_amdgcn_mfma_f32_16x16x32_bf16(a3_, BB1, acc[3][1], 0, 0, 0); \
    __builtin_amdgcn_s_setprio(0);                                                 \
} while (0)

// ---------------- k_sent: fused per-(b,n), 512 threads / 8 waves, 3 blocks/CU
// (round-2 verbatim body: measured 224 us, no spill, no device-scope fences)
__global__ __launch_bounds__(512, 6) void k_sent(
    const int* __restrict__ sentences, const int* __restrict__ question,
    const float* __restrict__ embeds,
    const unsigned short* __restrict__ filt_frag,
    const unsigned short* __restrict__ qe_frag,
    const unsigned short* __restrict__ qc_frag,
    const float* __restrict__ q_inv, const float* __restrict__ qc_inv,
    const float* __restrict__ W6, const float* __restrict__ b1,
    float* __restrict__ d_out) {
    const int blk = blockIdx.x;
    const int b = blk / NSS, n = blk - b * NSS;
    const int tid = threadIdx.x, lane = tid & 63, w = tid >> 6;     // w in [0,8)
    const int quad = lane >> 4, m16 = lane & 15;
    const int w2 = w * 2;

    __shared__ __align__(16) unsigned short seb[SROWS * SEST]; // 41,184 B; overlaid by scb after conv
    __shared__ __align__(16) float sim[LQQ * SIMST];           // 8,448 B
    __shared__ float sinv[64], scninv[64];
    __shared__ int sid[64];
    __shared__ int qid[LQQ];
    __shared__ float qm[LQQ], qiv[LQQ], qciv[LQQ];
    __shared__ float featq[LQQ][4];
    __shared__ float pr[LQQ];
    unsigned short* scb = seb;   // overlay: conv output [l][f] bf16 (60+4 zero rows x 264)

    // early prefetch of first conv B-fragments (independent of LDS)
    const bfrag* fF = (const bfrag*)filt_frag;
    bfrag b0a = fF[(w2) * 64 + lane];
    bfrag b0b = fF[(w2 + 1) * 64 + lane];

    const int* srow = sentences + ((size_t)b * NSS + n) * LSS;
    if (tid < 64) sid[tid] = (tid < LSS) ? srow[tid] : 0;
    if (tid < LQQ) {
        int qi = question[b * LQQ + tid];
        qid[tid] = qi; qm[tid] = qi > 0 ? 1.f : 0.f;
        qiv[tid] = q_inv[b * LQQ + tid]; qciv[tid] = qc_inv[b * LQQ + tid];
    }
    // zero seb row tails (d 300..311) and rows 60..65 (disjoint from gather region -> no barrier)
    {
        ushort4 z4 = {0, 0, 0, 0};
        for (int i = tid; i < 180; i += 512) {
            int r = i / 3, c = 300 + (i - r * 3) * 4;
            *(ushort4*)(seb + r * SEST + c) = z4;
        }
        for (int i = tid; i < 468; i += 512) {
            int r = i / 78, c = (i - r * 78) * 4;
            *(ushort4*)(seb + (60 + r) * SEST + c) = z4;
        }
    }
    // gather sentence embeddings -> bf16 LDS (token ids direct from global; L1-hot)
    for (int i = tid; i < LSS * 75; i += 512) {
        int r = i / 75, c = (i - r * 75) * 4;
        float4 v = *(const float4*)(embeds + (size_t)srow[r] * DD + c);
        ushort4 h;
        h.x = f2bf(v.x); h.y = f2bf(v.y); h.z = f2bf(v.z); h.w = f2bf(v.w);
        *(ushort4*)(seb + r * SEST + c) = h;
    }
    __syncthreads();
    // row inv-norms from bf16 (8 lanes per row, 480 threads), b128 reads
    if (tid < 480) {
        int r = tid >> 3, part = tid & 7;
        float s = 0.f;
        #pragma unroll
        for (int it = 0; it < 5; ++it) {
            if (!(it == 4 && part == 7)) {       // c=312 would cross into next row
                int c = part * 8 + it * 64;      // tails 300..311 are zero -> safe
                uint4 u = *(const uint4*)(seb + r * SEST + c);
                float a0 = bf2f((unsigned short)(u.x & 0xffff)), a1 = bf2f((unsigned short)(u.x >> 16));
                float a2 = bf2f((unsigned short)(u.y & 0xffff)), a3 = bf2f((unsigned short)(u.y >> 16));
                float a4 = bf2f((unsigned short)(u.z & 0xffff)), a5 = bf2f((unsigned short)(u.z >> 16));
                float a6 = bf2f((unsigned short)(u.w & 0xffff)), a7 = bf2f((unsigned short)(u.w >> 16));
                s += a0 * a0 + a1 * a1 + a2 * a2 + a3 * a3 + a4 * a4 + a5 * a5 + a6 * a6 + a7 * a7;
            }
        }
        s += __shfl_down(s, 4, 64);
        s += __shfl_down(s, 2, 64);
        s += __shfl_down(s, 1, 64);
        if (part == 0) sinv[r] = 1.f / sqrtf(s);
    }
    if (tid >= 480 && tid < 484) sinv[60 + tid - 480] = 0.f;
    __syncthreads();

    // ======== conv GEMM: C[l=64][f=256] = seb-window[64x928] x filt[928x256] ========
    // wave w owns N-tiles {2w, 2w+1}, all 4 M-tiles. Software-pipelined B prefetch (unroll-2).
    ffrag acc[4][2];
    #pragma unroll
    for (int mt = 0; mt < 4; ++mt)
        #pragma unroll
        for (int i = 0; i < 2; ++i) acc[mt][i] = (ffrag)0.f;
    {
        bfrag b1a, b1b;
        for (int kk = 0; kk + 2 <= KKC; kk += 2) {
            b1a = fF[((kk + 1) * 16 + w2) * 64 + lane];
            b1b = fF[((kk + 1) * 16 + w2 + 1) * 64 + lane];
            CONV_STEP(kk, b0a, b0b);
            if (kk + 2 < KKC) {
                b0a = fF[((kk + 2) * 16 + w2) * 64 + lane];
                b0b = fF[((kk + 2) * 16 + w2 + 1) * 64 + lane];
            }
            CONV_STEP(kk + 1, b1a, b1b);
        }
        CONV_STEP(KKC - 1, b0a, b0b);   // kk=28, loaded during kk=26 pair
    }
    // ======== sim_ins GEMM: C[q=32][l=64] = qe[32x320] x seb^T; wave w owns 1 tile ========
    {
        const int mt = w >> 2, nt = w & 3;
        const bfrag* qF = (const bfrag*)qe_frag + ((size_t)b * KKI * 2 + mt) * 64 + lane;
        const unsigned short* sebr = seb + (nt * 16 + m16) * SEST + quad * 8;
        ffrag c0 = (ffrag)0.f;
        bfrag aq0 = qF[0];
        for (int kk = 0; kk < KKI; kk += 2) {
            bfrag aq1 = qF[(kk + 1) * 128];
            bfrag bL0 = *(const bfrag*)(sebr + kk * 32);
            c0 = __builtin_amdgcn_mfma_f32_16x16x32_bf16(aq0, bL0, c0, 0, 0, 0);
            if (kk + 2 < KKI) aq0 = qF[(kk + 2) * 128];
            bfrag bL1 = *(const bfrag*)(sebr + (kk + 1) * 32);
            c0 = __builtin_amdgcn_mfma_f32_16x16x32_bf16(aq1, bL1, c0, 0, 0, 0);
        }
        const int l_ = nt * 16 + m16;
        const float sm = sinv[l_] * (sid[l_] > 0 ? 1.f : 0.f);
        #pragma unroll
        for (int r = 0; r < 4; ++r) {
            int q = mt * 16 + quad * 4 + r;
            sim[q * SIMST + l_] = c0[r] * (qiv[q] * qm[q]) * sm;
        }
    }
    __syncthreads();   // all seb reads done; sim_ins visible

    // ======== conv C -> scb bf16 [l][f] (overlays seb) + zero rows 60..63 + pool_ins ========
    if (tid < 256) {
        ushort4 z4 = {0, 0, 0, 0};
        int r4 = 60 + (tid >> 6), c4 = (tid & 63) * 4;
        *(ushort4*)(scb + r4 * SCST + c4) = z4;
    }
    #pragma unroll
    for (int mt = 0; mt < 4; ++mt)
        #pragma unroll
        for (int i = 0; i < 2; ++i) {
            int f = (w2 + i) * 16 + m16;
            #pragma unroll
            for (int r = 0; r < 4; ++r) {
                int l = mt * 16 + quad * 4 + r;
                scb[l * SCST + f] = f2bf(acc[mt][i][r]);
            }
        }
    if (tid < LQQ) {   // pool_ins + exact-match channel (integer equality, incl pad==pad, unmasked)
        int q = tid;
        float t0 = -1e30f, t1 = -1e30f, t2 = -1e30f, t3 = -1e30f, t4 = -1e30f;
        for (int l = 0; l < LSS; ++l) {
            float v = sim[q * SIMST + l];
            if (v > t4) {
                if (v > t0)      { t4 = t3; t3 = t2; t2 = t1; t1 = t0; t0 = v; }
                else if (v > t1) { t4 = t3; t3 = t2; t2 = t1; t1 = v; }
                else if (v > t2) { t4 = t3; t3 = t2; t2 = v; }
                else if (v > t3) { t4 = t3; t3 = v; }
                else               t4 = v;
            }
        }
        featq[q][0] = t0;
        featq[q][1] = (t0 + t1 + t2 + t3 + t4) * 0.2f;
        int qi = qid[q], c = 0;
        for (int l = 0; l < LSS; ++l) c += (sid[l] == qi) ? 1 : 0;
        featq[q][2] = c > 0 ? 1.f : 0.f;
        featq[q][3] = (float)(c < 5 ? c : 5) * 0.2f;
    }
    __syncthreads();
    // scb row inv-norms (8 lanes per row, 480 threads), b128 reads (FF=256 = 4 full iters)
    if (tid < 480) {
        int r = tid >> 3, part = tid & 7;
        float s = 0.f;
        #pragma unroll
        for (int it = 0; it < 4; ++it) {
            int c = part * 8 + it * 64;
            uint4 u = *(const uint4*)(scb + r * SCST + c);
            float a0 = bf2f((unsigned short)(u.x & 0xffff)), a1 = bf2f((unsigned short)(u.x >> 16));
            float a2 = bf2f((unsigned short)(u.y & 0xffff)), a3 = bf2f((unsigned short)(u.y >> 16));
            float a4 = bf2f((unsigned short)(u.z & 0xffff)), a5 = bf2f((unsigned short)(u.z >> 16));
            float a6 = bf2f((unsigned short)(u.w & 0xffff)), a7 = bf2f((unsigned short)(u.w >> 16));
            s += a0 * a0 + a1 * a1 + a2 * a2 + a3 * a3 + a4 * a4 + a5 * a5 + a6 * a6 + a7 * a7;
        }
        s += __shfl_down(s, 4, 64);
        s += __shfl_down(s, 2, 64);
        s += __shfl_down(s, 1, 64);
        if (part == 0) scninv[r] = 1.f / sqrtf(s);
    }
    if (tid >= 480 && tid < 484) scninv[60 + tid - 480] = 0.f;
    __syncthreads();
    // ======== sim_sen GEMM: C[q=32][l=64] = qc[32x256] x scb^T; wave w owns 1 tile ========
    {
        const int mt = w >> 2, nt = w & 3;
        const bfrag* qF = (const bfrag*)qc_frag + ((size_t)b * KKS * 2 + mt) * 64 + lane;
        const unsigned short* scbr = scb + (nt * 16 + m16) * SCST + quad * 8;
        ffrag c0 = (ffrag)0.f;
        bfrag aq0 = qF[0];
        for (int kk = 0; kk < KKS; kk += 2) {
            bfrag aq1 = qF[(kk + 1) * 128];
            bfrag bL0 = *(const bfrag*)(scbr + kk * 32);
            c0 = __builtin_amdgcn_mfma_f32_16x16x32_bf16(aq0, bL0, c0, 0, 0, 0);
            if (kk + 2 < KKS) aq0 = qF[(kk + 2) * 128];
            bfrag bL1 = *(const bfrag*)(scbr + (kk + 1) * 32);
            c0 = __builtin_amdgcn_mfma_f32_16x16x32_bf16(aq1, bL1, c0, 0, 0, 0);
        }
        const int l_ = nt * 16 + m16;
        const float sm = scninv[l_] * (sid[l_] > 0 ? 1.f : 0.f);
        #pragma unroll
        for (int r = 0; r < 4; ++r) {
            int q = mt * 16 + quad * 4 + r;
            sim[q * SIMST + l_] = c0[r] * (qciv[q] * qm[q]) * sm;
        }
    }
    __syncthreads();
    if (tid < LQQ) {   // pool_sen + linear + sigmoid
        int q = tid;
        float t0 = -1e30f, t1 = -1e30f, t2 = -1e30f, t3 = -1e30f, t4 = -1e30f;
        for (int l = 0; l < LSS; ++l) {
            float v = sim[q * SIMST + l];
            if (v > t4) {
                if (v > t0)      { t4 = t3; t3 = t2; t2 = t1; t1 = t0; t0 = v; }
                else if (v > t1) { t4 = t3; t3 = t2; t2 = t1; t1 = v; }
                else if (v > t2) { t4 = t3; t3 = t2; t2 = v; }
                else if (v > t3) { t4 = t3; t3 = v; }
                else               t4 = v;
            }
        }
        float smax = t0, smean = (t0 + t1 + t2 + t3 + t4) * 0.2f;
        float z = featq[q][0] * W6[0] + featq[q][1] * W6[1] + smax * W6[2] + smean * W6[3]
                + featq[q][2] * W6[4] + featq[q][3] * W6[5] + b1[0];
        pr[q] = 1.f / (1.f + expf(-z));
    }
    __syncthreads();
    if (w == 0) {
        float s = (lane < LQQ) ? pr[lane] : 0.f;
        s += __shfl_down(s, 16, 64);
        s += __shfl_down(s, 8, 64);
        s += __shfl_down(s, 4, 64);
        s += __shfl_down(s, 2, 64);
        s += __shfl_down(s, 1, 64);
        if (lane == 0) d_out[1 + (size_t)b * NSS + n] = s * (1.f / 32.f);
    }
}

// ---------------- k_final: doc max + both BCEs + loss
__global__ __launch_bounds__(256) void k_final(const int* __restrict__ tsent,
                                               const int* __restrict__ tdoc,
                                               float* __restrict__ d_out) {
    const int tid = threadIdx.x;
    __shared__ float sh[256];
    __shared__ float docs[VB];
    if (tid < VB) {
        float m = -1e30f;
        for (int nn = 0; nn < NSS; ++nn) m = fmaxf(m, d_out[1 + tid * NSS + nn]);
        docs[tid] = m;
        d_out[1 + VB * NSS + tid] = m;
    }
    float s = 0.f;
    for (int i = tid; i < VB * NSS; i += 256) {
        float p = d_out[1 + i];
        p = fminf(fmaxf(p, 1e-7f), 1.f - 1e-7f);
        float t = (float)tsent[i];
        s += t * logf(p) + (1.f - t) * log1pf(-p);
    }
    sh[tid] = s;
    __syncthreads();
    for (int st = 128; st > 0; st >>= 1) {
        if (tid < st) sh[tid] += sh[tid + st];
        __syncthreads();
    }
    float ls = 0.f;
    if (tid == 0) ls = -sh[0] / (float)(VB * NSS);
    __syncthreads();
    float s2 = 0.f;
    if (tid < VB) {
        float p = fminf(fmaxf(docs[tid], 1e-7f), 1.f - 1e-7f);
        float t = (float)tdoc[tid];
        s2 = t * logf(p) + (1.f - t) * log1pf(-p);
    }
    sh[tid] = s2;
    __syncthreads();
    for (int st = 128; st > 0; st >>= 1) {
        if (tid < st) sh[tid] += sh[tid + st];
        __syncthreads();
    }
    if (tid == 0) {
        float ld = -sh[0] / (float)VB;
        d_out[0] = 0.5f * (ls + ld);
    }
}

extern "C" void kernel_launch(void* const* d_in, const int* in_sizes, int n_in,
                              void* d_out, int out_size, void* d_ws, size_t ws_size,
                              hipStream_t stream) {
    const int*   sentences = (const int*)d_in[0];
    const int*   question  = (const int*)d_in[1];
    const int*   tsent     = (const int*)d_in[2];
    const int*   tdoc      = (const int*)d_in[3];
    const float* embeds    = (const float*)d_in[4];
    const float* filters   = (const float*)d_in[5];
    const float* W6        = (const float*)d_in[6];
    const float* b1        = (const float*)d_in[7];
    float* out = (float*)d_out;

    float* ws = (float*)d_ws;
    float* q_inv  = ws;                         // 2,048 f
    float* qc_inv = ws + 2048;                  // 2,048 f
    unsigned short* qe_frag  = (unsigned short*)(ws + 4096);      // 655,360 sh (16B-aligned)
    unsigned short* qc_frag  = qe_frag + 655360;                  // 524,288 sh
    unsigned short* filt_frag = qc_frag + 524288;                 // 237,568 sh  (total ~2.85 MB)

    k_fprep<<<232, 256, 0, stream>>>(filters, filt_frag);
    k_qprep<<<VB, 512, 0, stream>>>(question, embeds, filt_frag, qe_frag, qc_frag, q_inv, qc_inv);
    k_sent<<<VB * NSS, 512, 0, stream>>>(sentences, question, embeds,
                                         filt_frag, qe_frag, qc_frag,
                                         q_inv, qc_inv, W6, b1, out);
    k_final<<<1, 256, 0, stream>>>(tsent, tdoc, out);
}